// Round 1
// baseline (943.876 us; speedup 1.0000x reference)
//
#include <hip/hip_runtime.h>
#include <cmath>
#include <type_traits>

typedef unsigned short u16;
typedef float  f32x4 __attribute__((ext_vector_type(4)));
typedef short  s16x8 __attribute__((ext_vector_type(8)));
typedef __bf16 b16x8 __attribute__((ext_vector_type(8)));

constexpr int S_  = 1536;
constexpr int B_  = 2;
constexpr int D_  = 768;
constexpr int H_  = 24;
constexpr int DH_ = 32;
constexpr int FF_ = 3072;
constexpr int N_  = S_ * B_;      // 3072 tokens, row = s*B + b
constexpr int D3_ = 3 * D_;       // 2304
constexpr float SCALE_ = 0.17677669529663687f;  // 1/sqrt(32)

// ---- MFMA wrapper: works whether the builtin takes short8 or bf16x8 ----
template <typename T>
static __device__ inline auto mfma_try(T a, T b, f32x4 c, int)
    -> decltype(__builtin_amdgcn_mfma_f32_16x16x32_bf16(a, b, c, 0, 0, 0)) {
  return __builtin_amdgcn_mfma_f32_16x16x32_bf16(a, b, c, 0, 0, 0);
}
template <typename T>
static __device__ inline f32x4 mfma_try(T a, T b, f32x4 c, long) {
  b16x8 ab = __builtin_bit_cast(b16x8, a);
  b16x8 bb = __builtin_bit_cast(b16x8, b);
  return __builtin_amdgcn_mfma_f32_16x16x32_bf16(ab, bb, c, 0, 0, 0);
}
static __device__ inline f32x4 mfma_bf16(s16x8 a, s16x8 b, f32x4 c) {
  return mfma_try(a, b, c, 0);
}

static __device__ inline u16 f2bf(float f) {
  unsigned u = __builtin_bit_cast(unsigned, f);
  return (u16)((u + 0x7FFFu + ((u >> 16) & 1u)) >> 16);
}

static __device__ inline float rmax16(float v) {
  v = fmaxf(v, __shfl_xor(v, 1));
  v = fmaxf(v, __shfl_xor(v, 2));
  v = fmaxf(v, __shfl_xor(v, 4));
  v = fmaxf(v, __shfl_xor(v, 8));
  return v;
}
static __device__ inline float rsum16(float v) {
  v += __shfl_xor(v, 1);
  v += __shfl_xor(v, 2);
  v += __shfl_xor(v, 4);
  v += __shfl_xor(v, 8);
  return v;
}

// ---- weight fp32 -> bf16 conversion (one launch per layer) ----
__global__ void convert_weights_kernel(const float* __restrict__ wqkv,
                                       const float* __restrict__ wo,
                                       const float* __restrict__ wfc,
                                       const float* __restrict__ wproj,
                                       u16* __restrict__ dst) {
  constexpr int C0 = D3_ * D_;            // 1769472
  constexpr int C1 = C0 + D_ * D_;        // 2359296
  constexpr int C2 = C1 + FF_ * D_;       // 4718592
  constexpr int C3 = C2 + D_ * FF_;       // 7077888
  int i4 = (blockIdx.x * 256 + threadIdx.x) * 4;
  if (i4 >= C3) return;
  const float* src; int off;
  if (i4 < C0)      { src = wqkv;  off = i4; }
  else if (i4 < C1) { src = wo;    off = i4 - C0; }
  else if (i4 < C2) { src = wfc;   off = i4 - C1; }
  else              { src = wproj; off = i4 - C2; }
  float4 v = *(const float4*)(src + off);
  ushort4 o;
  o.x = f2bf(v.x); o.y = f2bf(v.y); o.z = f2bf(v.z); o.w = f2bf(v.w);
  *(ushort4*)(dst + i4) = o;
}

// ---- embedding gather: x[s*B+b, :] = wte[id] + wpe[pos], fp32 ----
__global__ void embed_kernel(const int* __restrict__ ids, const int* __restrict__ pos,
                             const float* __restrict__ wte, const float* __restrict__ wpe,
                             float* __restrict__ x) {
  int g  = blockIdx.x * 256 + threadIdx.x;  // N_*D_/4 threads
  int i4 = g * 4;
  int row = i4 / D_;
  int d   = i4 - row * D_;
  int s = row >> 1, b = row & 1;
  int t = ids[b * S_ + s];
  int p = pos[b * S_ + s];
  float4 a = *(const float4*)(wte + (size_t)t * D_ + d);
  float4 c = *(const float4*)(wpe + (size_t)p * D_ + d);
  a.x += c.x; a.y += c.y; a.z += c.z; a.w += c.w;
  *(float4*)(x + i4) = a;
}

// ---- LayerNorm: 1 wave per token, OUT = u16 (bf16) or float ----
template <typename OUT>
__global__ void ln_kernel(const float* __restrict__ x, const float* __restrict__ w,
                          const float* __restrict__ b, OUT* __restrict__ out) {
  int wid = threadIdx.x >> 6, lane = threadIdx.x & 63;
  int tok = blockIdx.x * 4 + wid;
  const float* xr = x + (size_t)tok * D_;
  float4 v[3];
  float s = 0.f, ss = 0.f;
#pragma unroll
  for (int c = 0; c < 3; ++c) {
    v[c] = *(const float4*)(xr + c * 256 + lane * 4);
    s  += v[c].x + v[c].y + v[c].z + v[c].w;
    ss += v[c].x * v[c].x + v[c].y * v[c].y + v[c].z * v[c].z + v[c].w * v[c].w;
  }
#pragma unroll
  for (int m = 1; m <= 32; m <<= 1) { s += __shfl_xor(s, m); ss += __shfl_xor(ss, m); }
  float mu = s * (1.0f / D_);
  float var = ss * (1.0f / D_) - mu * mu;
  float rs = rsqrtf(var + 1e-5f);
#pragma unroll
  for (int c = 0; c < 3; ++c) {
    int d = c * 256 + lane * 4;
    float o0 = (v[c].x - mu) * rs * w[d + 0] + b[d + 0];
    float o1 = (v[c].y - mu) * rs * w[d + 1] + b[d + 1];
    float o2 = (v[c].z - mu) * rs * w[d + 2] + b[d + 2];
    float o3 = (v[c].w - mu) * rs * w[d + 3] + b[d + 3];
    if constexpr (std::is_same_v<OUT, u16>) {
      ushort4 o; o.x = f2bf(o0); o.y = f2bf(o1); o.z = f2bf(o2); o.w = f2bf(o3);
      *(ushort4*)(out + (size_t)tok * D_ + d) = o;
    } else {
      float4 o; o.x = o0; o.y = o1; o.z = o2; o.w = o3;
      *(float4*)(out + (size_t)tok * D_ + d) = o;
    }
  }
}

// ---- Generic MFMA GEMM: C[tok, feat] = X[tok,:] . W[feat,:] + bias ----
// EPI 0: scatter to q/k/vt (bf16)   EPI 1: += residual, fp32 in/out (feat dim = D_)
// EPI 2: GELU -> bf16 (feat dim = FF_)
template <int BM, int BN, int EPI>
__launch_bounds__(256, 2)
__global__ void gemm_kernel(const u16* __restrict__ X, const u16* __restrict__ W,
                            const float* __restrict__ bias, int K,
                            u16* __restrict__ o0, u16* __restrict__ o1,
                            u16* __restrict__ o2, float* __restrict__ xio) {
  constexpr int AS = 40;  // padded LDS row stride (16B-aligned rows)
  constexpr int WM = BM / 2, WN = BN / 2, TM = WM / 16, TN = WN / 16;
  __shared__ u16 As[BM * AS];
  __shared__ u16 Bs[BN * AS];
  const int tid = threadIdx.x;
  const int wid = tid >> 6, lane = tid & 63;
  const int col = lane & 15, quad = lane >> 4;
  const int wm = wid & 1, wn = wid >> 1;
  const int rowA0 = blockIdx.x * BM;
  const int rowB0 = blockIdx.y * BN;

  f32x4 zz = {0.f, 0.f, 0.f, 0.f};
  f32x4 acc[TM][TN];
#pragma unroll
  for (int i = 0; i < TM; ++i)
#pragma unroll
    for (int j = 0; j < TN; ++j) acc[i][j] = zz;

  for (int k0 = 0; k0 < K; k0 += 32) {
#pragma unroll
    for (int it = 0; it < BM / 64; ++it) {
      int slot = tid + it * 256;
      int r = slot >> 2, c = slot & 3;
      *(uint4*)&As[r * AS + c * 8] = *(const uint4*)&X[(size_t)(rowA0 + r) * K + k0 + c * 8];
    }
#pragma unroll
    for (int it = 0; it < BN / 64; ++it) {
      int slot = tid + it * 256;
      int r = slot >> 2, c = slot & 3;
      *(uint4*)&Bs[r * AS + c * 8] = *(const uint4*)&W[(size_t)(rowB0 + r) * K + k0 + c * 8];
    }
    __syncthreads();
    s16x8 af[TM], bf[TN];
#pragma unroll
    for (int ti = 0; ti < TM; ++ti)
      af[ti] = *(const s16x8*)&As[(wm * WM + ti * 16 + col) * AS + quad * 8];
#pragma unroll
    for (int tj = 0; tj < TN; ++tj)
      bf[tj] = *(const s16x8*)&Bs[(wn * WN + tj * 16 + col) * AS + quad * 8];
#pragma unroll
    for (int ti = 0; ti < TM; ++ti)
#pragma unroll
      for (int tj = 0; tj < TN; ++tj)
        acc[ti][tj] = mfma_bf16(af[ti], bf[tj], acc[ti][tj]);
    __syncthreads();
  }

  const int tokBase  = rowA0 + wm * WM + quad * 4;
  const int featBase = rowB0 + wn * WN + col;
#pragma unroll
  for (int ti = 0; ti < TM; ++ti) {
#pragma unroll
    for (int tj = 0; tj < TN; ++tj) {
      int feat = featBase + tj * 16;
      float bv = bias[feat];
#pragma unroll
      for (int r = 0; r < 4; ++r) {
        int tok = tokBase + ti * 16 + r;
        float v = acc[ti][tj][r] + bv;
        if constexpr (EPI == 0) {
          int hh = feat / 96;
          int rem = feat - hh * 96;
          int comp = rem >> 5, d = rem & 31;
          int s = tok >> 1, bb = tok & 1;
          int bh = bb * H_ + hh;
          if (comp == 0)      o0[((size_t)bh * S_ + s) * DH_ + d] = f2bf(v);
          else if (comp == 1) o1[((size_t)bh * S_ + s) * DH_ + d] = f2bf(v);
          else                o2[((size_t)bh * DH_ + d) * S_ + s] = f2bf(v);
        } else if constexpr (EPI == 1) {
          float* p = xio + (size_t)tok * D_ + feat;
          *p = *p + v;
        } else {
          float g = 0.5f * v * (1.0f + erff(v * 0.70710678118654752f));
          o0[(size_t)tok * FF_ + feat] = f2bf(g);
        }
      }
    }
  }
}

// ---- flash attention: grid (S/64, B*H), block 256 (4 waves x 16 q-rows) ----
__launch_bounds__(256)
__global__ void attn_kernel(const u16* __restrict__ q, const u16* __restrict__ k,
                            const u16* __restrict__ vt, u16* __restrict__ ctx) {
  __shared__ u16 Plds[4][16 * 40];
  const int tid = threadIdx.x;
  const int wid = tid >> 6, lane = tid & 63;
  const int col = lane & 15, quad = lane >> 4;
  const int bh = blockIdx.y;
  const int bb = bh / H_, hh = bh - bb * H_;
  const u16* qb = q  + (size_t)bh * S_ * DH_;
  const u16* kb = k  + (size_t)bh * S_ * DH_;
  const u16* vb = vt + (size_t)bh * DH_ * S_;
  const int q0 = blockIdx.x * 64 + wid * 16;

  s16x8 qf = *(const s16x8*)&qb[(q0 + col) * DH_ + quad * 8];
  f32x4 zz = {0.f, 0.f, 0.f, 0.f};
  f32x4 o0 = zz, o1 = zz;
  float mr[4] = {-1e30f, -1e30f, -1e30f, -1e30f};
  float lr[4] = {0.f, 0.f, 0.f, 0.f};

  const int kend = blockIdx.x * 64 + 64;  // uniform across waves -> barriers safe
  for (int k0 = 0; k0 < kend; k0 += 32) {
    s16x8 kf0 = *(const s16x8*)&kb[(k0 + col) * DH_ + quad * 8];
    s16x8 kf1 = *(const s16x8*)&kb[(k0 + 16 + col) * DH_ + quad * 8];
    f32x4 s0 = mfma_bf16(qf, kf0, zz);
    f32x4 s1 = mfma_bf16(qf, kf1, zz);
#pragma unroll
    for (int r = 0; r < 4; ++r) {
      int qq = q0 + quad * 4 + r;
      float x0 = (k0 + col <= qq)      ? s0[r] * SCALE_ : -10000.0f;
      float x1 = (k0 + 16 + col <= qq) ? s1[r] * SCALE_ : -10000.0f;
      float cm = rmax16(fmaxf(x0, x1));
      float nm = fmaxf(mr[r], cm);
      float al = __expf(mr[r] - nm);
      float p0 = __expf(x0 - nm);
      float p1 = __expf(x1 - nm);
      float rs = rsum16(p0 + p1);
      lr[r] = lr[r] * al + rs;
      mr[r] = nm;
      o0[r] *= al; o1[r] *= al;
      Plds[wid][(quad * 4 + r) * 40 + col]      = f2bf(p0);
      Plds[wid][(quad * 4 + r) * 40 + 16 + col] = f2bf(p1);
    }
    __syncthreads();
    s16x8 pf  = *(const s16x8*)&Plds[wid][col * 40 + quad * 8];
    s16x8 vf0 = *(const s16x8*)&vb[(size_t)col * S_ + k0 + quad * 8];
    s16x8 vf1 = *(const s16x8*)&vb[(size_t)(16 + col) * S_ + k0 + quad * 8];
    o0 = mfma_bf16(pf, vf0, o0);
    o1 = mfma_bf16(pf, vf1, o1);
    __syncthreads();
  }
#pragma unroll
  for (int r = 0; r < 4; ++r) {
    int qq = q0 + quad * 4 + r;
    float inv = 1.0f / lr[r];
    size_t base = ((size_t)qq * B_ + bb) * D_ + hh * DH_;
    ctx[base + col]      = f2bf(o0[r] * inv);
    ctx[base + 16 + col] = f2bf(o1[r] * inv);
  }
}

extern "C" void kernel_launch(void* const* d_in, const int* in_sizes, int n_in,
                              void* d_out, int out_size, void* d_ws, size_t ws_size,
                              hipStream_t stream) {
  const int*   ids = (const int*)d_in[0];
  const int*   pos = (const int*)d_in[1];
  const float* wte = (const float*)d_in[3];
  const float* wpe = (const float*)d_in[4];
  const float* lnf_w = (const float*)d_in[29];
  const float* lnf_b = (const float*)d_in[30];

  // workspace layout (bytes)
  char* ws = (char*)d_ws;
  constexpr size_t SZ_X   = (size_t)N_ * D_ * 4;       // 9437184
  constexpr size_t SZ_H   = (size_t)N_ * D_ * 2;       // 4718592
  constexpr size_t SZ_QKV = (size_t)B_ * H_ * S_ * DH_ * 2;  // 4718592
  constexpr size_t SZ_M   = (size_t)N_ * FF_ * 2;      // 18874368
  constexpr int    WELEM  = D3_ * D_ + D_ * D_ + FF_ * D_ + D_ * FF_;  // 7077888

  float* xbuf = (float*)ws;
  u16* hbuf  = (u16*)(ws + SZ_X);
  u16* qbuf  = (u16*)(ws + SZ_X + SZ_H);
  u16* kbuf  = (u16*)(ws + SZ_X + SZ_H + SZ_QKV);
  u16* vtbuf = (u16*)(ws + SZ_X + SZ_H + 2 * SZ_QKV);
  u16* cbuf  = (u16*)(ws + SZ_X + SZ_H + 3 * SZ_QKV);
  u16* mbuf  = (u16*)(ws + SZ_X + SZ_H + 4 * SZ_QKV);
  u16* wbf   = (u16*)(ws + SZ_X + SZ_H + 4 * SZ_QKV + SZ_M);

  embed_kernel<<<N_ * D_ / 4 / 256, 256, 0, stream>>>(ids, pos, wte, wpe, xbuf);

  for (int l = 0; l < 2; ++l) {
    int p = 5 + l * 12;
    const float* ln1w  = (const float*)d_in[p + 0];
    const float* ln1b  = (const float*)d_in[p + 1];
    const float* wqkv  = (const float*)d_in[p + 2];
    const float* bqkv  = (const float*)d_in[p + 3];
    const float* wo    = (const float*)d_in[p + 4];
    const float* bo    = (const float*)d_in[p + 5];
    const float* ln2w  = (const float*)d_in[p + 6];
    const float* ln2b  = (const float*)d_in[p + 7];
    const float* wfc   = (const float*)d_in[p + 8];
    const float* bfc   = (const float*)d_in[p + 9];
    const float* wproj = (const float*)d_in[p + 10];
    const float* bproj = (const float*)d_in[p + 11];

    u16* wb = wbf + (size_t)l * WELEM;
    u16* wqkv_b  = wb;
    u16* wo_b    = wb + D3_ * D_;
    u16* wfc_b   = wb + D3_ * D_ + D_ * D_;
    u16* wproj_b = wb + D3_ * D_ + D_ * D_ + FF_ * D_;

    convert_weights_kernel<<<WELEM / 4 / 256, 256, 0, stream>>>(wqkv, wo, wfc, wproj, wb);

    // LN1 -> h
    ln_kernel<u16><<<N_ / 4, 256, 0, stream>>>(xbuf, ln1w, ln1b, hbuf);
    // QKV: (3072 x 768) @ (2304 x 768)^T, scatter to q/k/vt
    gemm_kernel<128, 128, 0><<<dim3(N_ / 128, D3_ / 128), 256, 0, stream>>>(
        hbuf, wqkv_b, bqkv, D_, qbuf, kbuf, vtbuf, nullptr);
    // attention -> ctx
    attn_kernel<<<dim3(S_ / 64, B_ * H_), 256, 0, stream>>>(qbuf, kbuf, vtbuf, cbuf);
    // WO + residual -> x
    gemm_kernel<128, 64, 1><<<dim3(N_ / 128, D_ / 64), 256, 0, stream>>>(
        cbuf, wo_b, bo, D_, nullptr, nullptr, nullptr, xbuf);
    // LN2 -> h
    ln_kernel<u16><<<N_ / 4, 256, 0, stream>>>(xbuf, ln2w, ln2b, hbuf);
    // FC + GELU -> m
    gemm_kernel<128, 128, 2><<<dim3(N_ / 128, FF_ / 128), 256, 0, stream>>>(
        hbuf, wfc_b, bfc, D_, mbuf, nullptr, nullptr, nullptr);
    // PROJ + residual -> x
    gemm_kernel<128, 64, 1><<<dim3(N_ / 128, D_ / 64), 256, 0, stream>>>(
        mbuf, wproj_b, bproj, FF_, nullptr, nullptr, nullptr, xbuf);
  }

  // final LN -> d_out (fp32)
  ln_kernel<float><<<N_ / 4, 256, 0, stream>>>(xbuf, lnf_w, lnf_b, (float*)d_out);
}

// Round 2
// 840.009 us; speedup vs baseline: 1.1236x; 1.1236x over previous
//
#include <hip/hip_runtime.h>
#include <cmath>
#include <type_traits>

typedef unsigned short u16;
typedef float  f32x4 __attribute__((ext_vector_type(4)));
typedef short  s16x8 __attribute__((ext_vector_type(8)));
typedef __bf16 b16x8 __attribute__((ext_vector_type(8)));

#define GLOBAL_AS __attribute__((address_space(1)))
#define LDS_AS    __attribute__((address_space(3)))

constexpr int S_  = 1536;
constexpr int B_  = 2;
constexpr int D_  = 768;
constexpr int H_  = 24;
constexpr int DH_ = 32;
constexpr int FF_ = 3072;
constexpr int N_  = S_ * B_;      // 3072 tokens, row = s*B + b
constexpr int D3_ = 3 * D_;       // 2304
constexpr float SCALE_ = 0.17677669529663687f;  // 1/sqrt(32)

// ---- MFMA wrapper: works whether the builtin takes short8 or bf16x8 ----
template <typename T>
static __device__ inline auto mfma_try(T a, T b, f32x4 c, int)
    -> decltype(__builtin_amdgcn_mfma_f32_16x16x32_bf16(a, b, c, 0, 0, 0)) {
  return __builtin_amdgcn_mfma_f32_16x16x32_bf16(a, b, c, 0, 0, 0);
}
template <typename T>
static __device__ inline f32x4 mfma_try(T a, T b, f32x4 c, long) {
  b16x8 ab = __builtin_bit_cast(b16x8, a);
  b16x8 bb = __builtin_bit_cast(b16x8, b);
  return __builtin_amdgcn_mfma_f32_16x16x32_bf16(ab, bb, c, 0, 0, 0);
}
static __device__ inline f32x4 mfma_bf16(s16x8 a, s16x8 b, f32x4 c) {
  return mfma_try(a, b, c, 0);
}

static __device__ inline u16 f2bf(float f) {
  unsigned u = __builtin_bit_cast(unsigned, f);
  return (u16)((u + 0x7FFFu + ((u >> 16) & 1u)) >> 16);
}

static __device__ inline float rmax16(float v) {
  v = fmaxf(v, __shfl_xor(v, 1));
  v = fmaxf(v, __shfl_xor(v, 2));
  v = fmaxf(v, __shfl_xor(v, 4));
  v = fmaxf(v, __shfl_xor(v, 8));
  return v;
}
static __device__ inline float rsum16(float v) {
  v += __shfl_xor(v, 1);
  v += __shfl_xor(v, 2);
  v += __shfl_xor(v, 4);
  v += __shfl_xor(v, 8);
  return v;
}

// ---- weight fp32 -> bf16 conversion (one launch per layer) ----
__global__ void convert_weights_kernel(const float* __restrict__ wqkv,
                                       const float* __restrict__ wo,
                                       const float* __restrict__ wfc,
                                       const float* __restrict__ wproj,
                                       u16* __restrict__ dst) {
  constexpr int C0 = D3_ * D_;            // 1769472
  constexpr int C1 = C0 + D_ * D_;        // 2359296
  constexpr int C2 = C1 + FF_ * D_;       // 4718592
  constexpr int C3 = C2 + D_ * FF_;       // 7077888
  int i4 = (blockIdx.x * 256 + threadIdx.x) * 4;
  if (i4 >= C3) return;
  const float* src; int off;
  if (i4 < C0)      { src = wqkv;  off = i4; }
  else if (i4 < C1) { src = wo;    off = i4 - C0; }
  else if (i4 < C2) { src = wfc;   off = i4 - C1; }
  else              { src = wproj; off = i4 - C2; }
  float4 v = *(const float4*)(src + off);
  ushort4 o;
  o.x = f2bf(v.x); o.y = f2bf(v.y); o.z = f2bf(v.z); o.w = f2bf(v.w);
  *(ushort4*)(dst + i4) = o;
}

// ---- embedding gather: x[s*B+b, :] = wte[id] + wpe[pos], fp32 ----
__global__ void embed_kernel(const int* __restrict__ ids, const int* __restrict__ pos,
                             const float* __restrict__ wte, const float* __restrict__ wpe,
                             float* __restrict__ x) {
  int g  = blockIdx.x * 256 + threadIdx.x;  // N_*D_/4 threads
  int i4 = g * 4;
  int row = i4 / D_;
  int d   = i4 - row * D_;
  int s = row >> 1, b = row & 1;
  int t = ids[b * S_ + s];
  int p = pos[b * S_ + s];
  float4 a = *(const float4*)(wte + (size_t)t * D_ + d);
  float4 c = *(const float4*)(wpe + (size_t)p * D_ + d);
  a.x += c.x; a.y += c.y; a.z += c.z; a.w += c.w;
  *(float4*)(x + i4) = a;
}

// ---- LayerNorm: 1 wave per token, OUT = u16 (bf16) or float ----
template <typename OUT>
__global__ void ln_kernel(const float* __restrict__ x, const float* __restrict__ w,
                          const float* __restrict__ b, OUT* __restrict__ out) {
  int wid = threadIdx.x >> 6, lane = threadIdx.x & 63;
  int tok = blockIdx.x * 4 + wid;
  const float* xr = x + (size_t)tok * D_;
  float4 v[3];
  float s = 0.f, ss = 0.f;
#pragma unroll
  for (int c = 0; c < 3; ++c) {
    v[c] = *(const float4*)(xr + c * 256 + lane * 4);
    s  += v[c].x + v[c].y + v[c].z + v[c].w;
    ss += v[c].x * v[c].x + v[c].y * v[c].y + v[c].z * v[c].z + v[c].w * v[c].w;
  }
#pragma unroll
  for (int m = 1; m <= 32; m <<= 1) { s += __shfl_xor(s, m); ss += __shfl_xor(ss, m); }
  float mu = s * (1.0f / D_);
  float var = ss * (1.0f / D_) - mu * mu;
  float rs = rsqrtf(var + 1e-5f);
#pragma unroll
  for (int c = 0; c < 3; ++c) {
    int d = c * 256 + lane * 4;
    float o0 = (v[c].x - mu) * rs * w[d + 0] + b[d + 0];
    float o1 = (v[c].y - mu) * rs * w[d + 1] + b[d + 1];
    float o2 = (v[c].z - mu) * rs * w[d + 2] + b[d + 2];
    float o3 = (v[c].w - mu) * rs * w[d + 3] + b[d + 3];
    if constexpr (std::is_same_v<OUT, u16>) {
      ushort4 o; o.x = f2bf(o0); o.y = f2bf(o1); o.z = f2bf(o2); o.w = f2bf(o3);
      *(ushort4*)(out + (size_t)tok * D_ + d) = o;
    } else {
      float4 o; o.x = o0; o.y = o1; o.z = o2; o.w = o3;
      *(float4*)(out + (size_t)tok * D_ + d) = o;
    }
  }
}

// ---- Generic MFMA GEMM: C[tok, feat] = X[tok,:] . W[feat,:] + bias ----
// BK=64, global_load_lds(16B) staging, XOR-3 chunk swizzle (conflict-free
// ds_read_b128: LDS position p holds k-chunk p^(row&7); row stride 128 B,
// every 8 consecutive lanes cover all 32 banks exactly once).
// EPI 0: scatter to q/k/vt (bf16)   EPI 1: += residual, fp32 in/out
// EPI 2: GELU -> bf16 (feat dim = FF_)
template <int BM, int BN, int EPI>
__launch_bounds__(256, 3)
__global__ void gemm_kernel(const u16* __restrict__ X, const u16* __restrict__ W,
                            const float* __restrict__ bias, int K,
                            u16* __restrict__ o0, u16* __restrict__ o1,
                            u16* __restrict__ o2, float* __restrict__ xio) {
  constexpr int BK = 64;
  constexpr int WM = BM / 2, WN = BN / 2, TM = WM / 16, TN = WN / 16;
  __shared__ u16 As[BM * BK];
  __shared__ u16 Bs[BN * BK];
  const int tid = threadIdx.x;
  const int wid = tid >> 6, lane = tid & 63;
  const int col = lane & 15, quad = lane >> 4;
  const int wm = wid & 1, wn = wid >> 1;
  const int rowA0 = blockIdx.x * BM;
  const int rowB0 = blockIdx.y * BN;

  f32x4 zz = {0.f, 0.f, 0.f, 0.f};
  f32x4 acc[TM][TN];
#pragma unroll
  for (int i = 0; i < TM; ++i)
#pragma unroll
    for (int j = 0; j < TN; ++j) acc[i][j] = zz;

  for (int k0 = 0; k0 < K; k0 += BK) {
    // stage A: BM*8 16B-slots; slot s=(r*8+p) holds chunk c=p^(r&7) of row r
#pragma unroll
    for (int it = 0; it < BM / 32; ++it) {
      int bs = (it * 4 + wid) * 64;          // wave-uniform base slot
      int slot = bs + lane;
      int r = slot >> 3;
      int c = (slot & 7) ^ (r & 7);
      const u16* g = &X[(size_t)(rowA0 + r) * K + k0 + c * 8];
      __builtin_amdgcn_global_load_lds((const GLOBAL_AS unsigned int*)g,
                                       (LDS_AS unsigned int*)&As[bs * 8], 16, 0, 0);
    }
#pragma unroll
    for (int it = 0; it < BN / 32; ++it) {
      int bs = (it * 4 + wid) * 64;
      int slot = bs + lane;
      int r = slot >> 3;
      int c = (slot & 7) ^ (r & 7);
      const u16* g = &W[(size_t)(rowB0 + r) * K + k0 + c * 8];
      __builtin_amdgcn_global_load_lds((const GLOBAL_AS unsigned int*)g,
                                       (LDS_AS unsigned int*)&Bs[bs * 8], 16, 0, 0);
    }
    __syncthreads();
#pragma unroll
    for (int kb = 0; kb < 2; ++kb) {
      s16x8 af[TM], bf[TN];
#pragma unroll
      for (int ti = 0; ti < TM; ++ti) {
        int row = wm * WM + ti * 16 + col;
        af[ti] = *(const s16x8*)&As[row * BK + ((kb * 4 + quad) ^ (row & 7)) * 8];
      }
#pragma unroll
      for (int tj = 0; tj < TN; ++tj) {
        int row = wn * WN + tj * 16 + col;
        bf[tj] = *(const s16x8*)&Bs[row * BK + ((kb * 4 + quad) ^ (row & 7)) * 8];
      }
#pragma unroll
      for (int ti = 0; ti < TM; ++ti)
#pragma unroll
        for (int tj = 0; tj < TN; ++tj)
          acc[ti][tj] = mfma_bf16(af[ti], bf[tj], acc[ti][tj]);
    }
    __syncthreads();
  }

  const int tokBase  = rowA0 + wm * WM + quad * 4;
  const int featBase = rowB0 + wn * WN + col;
#pragma unroll
  for (int ti = 0; ti < TM; ++ti) {
#pragma unroll
    for (int tj = 0; tj < TN; ++tj) {
      int feat = featBase + tj * 16;
      float bv = bias[feat];
#pragma unroll
      for (int r = 0; r < 4; ++r) {
        int tok = tokBase + ti * 16 + r;
        float v = acc[ti][tj][r] + bv;
        if constexpr (EPI == 0) {
          int hh = feat / 96;
          int rem = feat - hh * 96;
          int comp = rem >> 5, d = rem & 31;
          int s = tok >> 1, bb = tok & 1;
          int bh = bb * H_ + hh;
          if (comp == 0)      o0[((size_t)bh * S_ + s) * DH_ + d] = f2bf(v);
          else if (comp == 1) o1[((size_t)bh * S_ + s) * DH_ + d] = f2bf(v);
          else                o2[((size_t)bh * DH_ + d) * S_ + s] = f2bf(v);
        } else if constexpr (EPI == 1) {
          float* p = xio + (size_t)tok * D_ + feat;
          *p = *p + v;
        } else {
          float g = 0.5f * v * (1.0f + erff(v * 0.70710678118654752f));
          o0[(size_t)tok * FF_ + feat] = f2bf(g);
        }
      }
    }
  }
}

// ---- flash attention: grid (S/64, B*H), block 256; each wave owns 16 q-rows.
// All LDS traffic (P relayout) is wave-private -> NO block barriers; per-wave
// causal bound. LDS ops within a wave execute in order; waitcnt+wave_barrier
// pin the write->read ordering against compiler motion.
__launch_bounds__(256)
__global__ void attn_kernel(const u16* __restrict__ q, const u16* __restrict__ k,
                            const u16* __restrict__ vt, u16* __restrict__ ctx) {
  __shared__ u16 Plds[4][16 * 40];
  const int tid = threadIdx.x;
  const int wid = tid >> 6, lane = tid & 63;
  const int col = lane & 15, quad = lane >> 4;
  const int bh = blockIdx.y;
  const int bb = bh / H_, hh = bh - bb * H_;
  const u16* qb = q  + (size_t)bh * S_ * DH_;
  const u16* kb = k  + (size_t)bh * S_ * DH_;
  const u16* vb = vt + (size_t)bh * DH_ * S_;
  const int q0 = blockIdx.x * 64 + wid * 16;

  s16x8 qf = *(const s16x8*)&qb[(q0 + col) * DH_ + quad * 8];
  f32x4 zz = {0.f, 0.f, 0.f, 0.f};
  f32x4 o0 = zz, o1 = zz;
  float mr[4] = {-1e30f, -1e30f, -1e30f, -1e30f};
  float lr[4] = {0.f, 0.f, 0.f, 0.f};

  const int kend = q0 + 16;  // per-wave causal end (no block barriers)
  for (int k0 = 0; k0 < kend; k0 += 32) {
    s16x8 kf0 = *(const s16x8*)&kb[(k0 + col) * DH_ + quad * 8];
    s16x8 kf1 = *(const s16x8*)&kb[(k0 + 16 + col) * DH_ + quad * 8];
    f32x4 s0 = mfma_bf16(qf, kf0, zz);
    f32x4 s1 = mfma_bf16(qf, kf1, zz);
#pragma unroll
    for (int r = 0; r < 4; ++r) {
      int qq = q0 + quad * 4 + r;
      float x0 = (k0 + col <= qq)      ? s0[r] * SCALE_ : -10000.0f;
      float x1 = (k0 + 16 + col <= qq) ? s1[r] * SCALE_ : -10000.0f;
      float cm = rmax16(fmaxf(x0, x1));
      float nm = fmaxf(mr[r], cm);
      float al = __expf(mr[r] - nm);
      float p0 = __expf(x0 - nm);
      float p1 = __expf(x1 - nm);
      float rs = rsum16(p0 + p1);
      lr[r] = lr[r] * al + rs;
      mr[r] = nm;
      o0[r] *= al; o1[r] *= al;
      Plds[wid][(quad * 4 + r) * 40 + col]      = f2bf(p0);
      Plds[wid][(quad * 4 + r) * 40 + 16 + col] = f2bf(p1);
    }
    __builtin_amdgcn_wave_barrier();
    __builtin_amdgcn_s_waitcnt(0xc07f);  // lgkmcnt(0): P writes retired
    __builtin_amdgcn_wave_barrier();
    s16x8 pf  = *(const s16x8*)&Plds[wid][col * 40 + quad * 8];
    s16x8 vf0 = *(const s16x8*)&vb[(size_t)col * S_ + k0 + quad * 8];
    s16x8 vf1 = *(const s16x8*)&vb[(size_t)(16 + col) * S_ + k0 + quad * 8];
    o0 = mfma_bf16(pf, vf0, o0);
    o1 = mfma_bf16(pf, vf1, o1);
    __builtin_amdgcn_wave_barrier();
  }
#pragma unroll
  for (int r = 0; r < 4; ++r) {
    float inv = 1.0f / lr[r];
    int qq = q0 + quad * 4 + r;
    size_t base = ((size_t)qq * B_ + bb) * D_ + hh * DH_;
    ctx[base + col]      = f2bf(o0[r] * inv);
    ctx[base + 16 + col] = f2bf(o1[r] * inv);
  }
}

extern "C" void kernel_launch(void* const* d_in, const int* in_sizes, int n_in,
                              void* d_out, int out_size, void* d_ws, size_t ws_size,
                              hipStream_t stream) {
  const int*   ids = (const int*)d_in[0];
  const int*   pos = (const int*)d_in[1];
  const float* wte = (const float*)d_in[3];
  const float* wpe = (const float*)d_in[4];
  const float* lnf_w = (const float*)d_in[29];
  const float* lnf_b = (const float*)d_in[30];

  // workspace layout (bytes)
  char* ws = (char*)d_ws;
  constexpr size_t SZ_X   = (size_t)N_ * D_ * 4;       // 9437184
  constexpr size_t SZ_H   = (size_t)N_ * D_ * 2;       // 4718592
  constexpr size_t SZ_QKV = (size_t)B_ * H_ * S_ * DH_ * 2;  // 4718592
  constexpr size_t SZ_M   = (size_t)N_ * FF_ * 2;      // 18874368
  constexpr int    WELEM  = D3_ * D_ + D_ * D_ + FF_ * D_ + D_ * FF_;  // 7077888

  float* xbuf = (float*)ws;
  u16* hbuf  = (u16*)(ws + SZ_X);
  u16* qbuf  = (u16*)(ws + SZ_X + SZ_H);
  u16* kbuf  = (u16*)(ws + SZ_X + SZ_H + SZ_QKV);
  u16* vtbuf = (u16*)(ws + SZ_X + SZ_H + 2 * SZ_QKV);
  u16* cbuf  = (u16*)(ws + SZ_X + SZ_H + 3 * SZ_QKV);
  u16* mbuf  = (u16*)(ws + SZ_X + SZ_H + 4 * SZ_QKV);
  u16* wbf   = (u16*)(ws + SZ_X + SZ_H + 4 * SZ_QKV + SZ_M);

  embed_kernel<<<N_ * D_ / 4 / 256, 256, 0, stream>>>(ids, pos, wte, wpe, xbuf);

  for (int l = 0; l < 2; ++l) {
    int p = 5 + l * 12;
    const float* ln1w  = (const float*)d_in[p + 0];
    const float* ln1b  = (const float*)d_in[p + 1];
    const float* wqkv  = (const float*)d_in[p + 2];
    const float* bqkv  = (const float*)d_in[p + 3];
    const float* wo    = (const float*)d_in[p + 4];
    const float* bo    = (const float*)d_in[p + 5];
    const float* ln2w  = (const float*)d_in[p + 6];
    const float* ln2b  = (const float*)d_in[p + 7];
    const float* wfc   = (const float*)d_in[p + 8];
    const float* bfc   = (const float*)d_in[p + 9];
    const float* wproj = (const float*)d_in[p + 10];
    const float* bproj = (const float*)d_in[p + 11];

    u16* wb = wbf + (size_t)l * WELEM;
    u16* wqkv_b  = wb;
    u16* wo_b    = wb + D3_ * D_;
    u16* wfc_b   = wb + D3_ * D_ + D_ * D_;
    u16* wproj_b = wb + D3_ * D_ + D_ * D_ + FF_ * D_;

    convert_weights_kernel<<<WELEM / 4 / 256, 256, 0, stream>>>(wqkv, wo, wfc, wproj, wb);

    // LN1 -> h
    ln_kernel<u16><<<N_ / 4, 256, 0, stream>>>(xbuf, ln1w, ln1b, hbuf);
    // QKV: (3072 x 768) @ (2304 x 768)^T, scatter to q/k/vt
    gemm_kernel<128, 128, 0><<<dim3(N_ / 128, D3_ / 128), 256, 0, stream>>>(
        hbuf, wqkv_b, bqkv, D_, qbuf, kbuf, vtbuf, nullptr);
    // attention -> ctx
    attn_kernel<<<dim3(S_ / 64, B_ * H_), 256, 0, stream>>>(qbuf, kbuf, vtbuf, cbuf);
    // WO + residual -> x
    gemm_kernel<128, 64, 1><<<dim3(N_ / 128, D_ / 64), 256, 0, stream>>>(
        cbuf, wo_b, bo, D_, nullptr, nullptr, nullptr, xbuf);
    // LN2 -> h
    ln_kernel<u16><<<N_ / 4, 256, 0, stream>>>(xbuf, ln2w, ln2b, hbuf);
    // FC + GELU -> m
    gemm_kernel<128, 128, 2><<<dim3(N_ / 128, FF_ / 128), 256, 0, stream>>>(
        hbuf, wfc_b, bfc, D_, mbuf, nullptr, nullptr, nullptr);
    // PROJ + residual -> x
    gemm_kernel<128, 64, 1><<<dim3(N_ / 128, D_ / 64), 256, 0, stream>>>(
        mbuf, wproj_b, bproj, FF_, nullptr, nullptr, nullptr, xbuf);
  }

  // final LN -> d_out (fp32)
  ln_kernel<float><<<N_ / 4, 256, 0, stream>>>(xbuf, lnf_w, lnf_b, (float*)d_out);
}